// Round 4
// baseline (566.009 us; speedup 1.0000x reference)
//
#include <hip/hip_runtime.h>
#include <cmath>

#define D_MODEL 1792
#define BB      256
#define II      2048          // inner dim
#define FOURI   8192

__device__ __forceinline__ float sigm(float v) { return 1.0f / (1.0f + expf(-v)); }

__device__ __forceinline__ float waveReduce(float s) {
    #pragma unroll
    for (int off = 32; off > 0; off >>= 1) s += __shfl_down(s, off, 64);
    return s;
}

// dot of one 2048-wide weight row with concat(x_t[1792], y_t[256])
__device__ __forceinline__ float dotConcat(const float* __restrict__ wrow,
                                           const float* __restrict__ xt,
                                           const float* __restrict__ yt,
                                           int lane) {
    float sum = 0.f;
    #pragma unroll
    for (int p = 0; p < 8; ++p) {
        const int j = p * 256 + lane * 4;
        float4 w = *(const float4*)(wrow + j);
        float4 v = (p < 7) ? *(const float4*)(xt + j)
                           : *(const float4*)(yt + (j - D_MODEL));
        sum += w.x * v.x + w.y * v.y + w.z * v.z + w.w * v.w;
    }
    return sum;
}

// dot of one 2048-wide weight row with a contiguous 2048 vector
__device__ __forceinline__ float dotH(const float* __restrict__ wrow,
                                      const float* __restrict__ h,
                                      int lane) {
    float sum = 0.f;
    #pragma unroll
    for (int p = 0; p < 8; ++p) {
        const int j = p * 256 + lane * 4;
        float4 w = *(const float4*)(wrow + j);
        float4 v = *(const float4*)(h + j);
        sum += w.x * v.x + w.y * v.y + w.z * v.z + w.w * v.w;
    }
    return sum;
}

__global__ __launch_bounds__(256, 4) void lstm_pipe(
    const float* __restrict__ x,     // (6,1792)
    const float* __restrict__ y,     // (5,256)
    const float* __restrict__ Wih5,  // (5,8192,2048)
    const float* __restrict__ Whh5,  // (5,8192,2048)
    const float* __restrict__ bih5,  // (5,8192)
    const float* __restrict__ bhh5,  // (5,8192)
    const float* __restrict__ WihF,  // (8192,1792)
    const float* __restrict__ WhhF,  // (8192,2048)
    const float* __restrict__ bihF,  // (8192)
    const float* __restrict__ bhhF,  // (8192)
    float* __restrict__ out,         // (256)
    float* __restrict__ gihAll,      // (4,8192) gih for steps 1..4
    float* __restrict__ gihF,        // (1024) compact [gate][256]
    float* __restrict__ hbuf,        // (5,2048)
    float* __restrict__ cbuf,        // (2048)
    int* __restrict__ ctl,           // [0] = barrier counter (pre-zeroed)
    int G)                           // grid size (co-resident by construction)
{
    const int b    = blockIdx.x;
    const int tid  = threadIdx.x;
    const int wave = tid >> 6;
    const int lane = tid & 63;
    __shared__ float partial[4];

    // ---- monotonic-counter grid barrier (all G blocks co-resident) ----
    auto gridbar = [&](int target) {
        __syncthreads();
        if (tid == 0) {
            __threadfence();  // flush this block's stores device-wide
            __hip_atomic_fetch_add(ctl, 1, __ATOMIC_RELEASE,
                                   __HIP_MEMORY_SCOPE_AGENT);
            while (__hip_atomic_load(ctl, __ATOMIC_ACQUIRE,
                                     __HIP_MEMORY_SCOPE_AGENT) < target)
                __builtin_amdgcn_s_sleep(16);
            __threadfence();  // invalidate caches: see other blocks' stores
        }
        __syncthreads();
    };

    // ---- one full cell row r for step t (one wave does all 4 gate dots) ----
    auto cell_row = [&](int t, int r) {
        float g[4];
        if (t == 0) {
            #pragma unroll
            for (int q = 0; q < 4; ++q) {
                if (q == 1) { g[1] = 0.f; continue; }   // f-gate unused (c0=0)
                const float* wrow = Wih5 + ((size_t)q * II + r) * (size_t)II;
                float s = dotConcat(wrow, x, y, lane);
                s = waveReduce(s);
                g[q] = s + bih5[q * II + r] + bhh5[q * II + r];
            }
            if (lane == 0) {
                const float cc = sigm(g[0]) * tanhf(g[2]);
                cbuf[r] = cc;
                hbuf[r] = sigm(g[3]) * tanhf(cc);
            }
        } else {
            const float* h  = hbuf + (size_t)(t - 1) * II;
            const float* W  = Whh5 + (size_t)t * FOURI * II;
            const float* gt = gihAll + (size_t)(t - 1) * FOURI;
            #pragma unroll
            for (int q = 0; q < 4; ++q) {
                const float* wrow = W + ((size_t)q * II + r) * (size_t)II;
                float s = dotH(wrow, h, lane);
                s = waveReduce(s);
                g[q] = s + gt[q * II + r];
            }
            if (lane == 0) {
                const float cc = sigm(g[1]) * cbuf[r] + sigm(g[0]) * tanhf(g[2]);
                cbuf[r] = cc;
                hbuf[(size_t)t * II + r] = sigm(g[3]) * tanhf(cc);
            }
        }
    };

    // ---- one ih row (raw row index 0..8191) for step tt in 1..4 ----
    auto ih_row = [&](int tt, int row) {
        const float* wrow = Wih5 + ((size_t)tt * FOURI + row) * (size_t)II;
        float s = dotConcat(wrow, x + tt * D_MODEL, y + tt * BB, lane);
        s = waveReduce(s);
        if (lane == 0)
            gihAll[(size_t)(tt - 1) * FOURI + row] =
                s + bih5[tt * FOURI + row] + bhh5[tt * FOURI + row];
    };

    // ---- one final-cell ih row, j in [0,1024): gate=j>>8, col=j&255 ----
    auto ihF_row = [&](int j) {
        const int row = (j >> 8) * II + D_MODEL + (j & 255);
        const float* wrow = WihF + (size_t)row * (size_t)D_MODEL;
        const float* x5 = x + 5 * D_MODEL;
        float s = 0.f;
        #pragma unroll
        for (int p = 0; p < 7; ++p) {
            const int jj = p * 256 + lane * 4;
            float4 w = *(const float4*)(wrow + jj);
            float4 v = *(const float4*)(x5 + jj);
            s += w.x * v.x + w.y * v.y + w.z * v.z + w.w * v.w;
        }
        s = waveReduce(s);
        if (lane == 0) gihF[j] = s + bihF[row] + bhhF[row];
    };

    // ================= 5 phases: cell t (waves 0-1) + ih filler (waves 2-3) =
    for (int t = 0; t < 5; ++t) {
        if (wave < 2) {
            for (int r = 2 * b + wave; r < II; r += 2 * G)
                cell_row(t, r);
        } else if (t < 4) {
            // ih for step t+1: 8192 rows; block j owns rows 8j..8j+7,
            // waves 2,3 take 4 contiguous rows each (32KB streams)
            for (int j = b; j < 1024; j += G) {
                const int base = j * 8 + (wave - 2) * 4;
                #pragma unroll
                for (int k = 0; k < 4; ++k) ih_row(t + 1, base + k);
            }
        } else if (wave == 2) {
            // phase 4 filler: final-cell ih rows (needed only after barrier 5)
            for (int j = b; j < 1024; j += G) ihF_row(j);
        }
        gridbar((t + 1) * G);
    }

    // ================= final cell: rows 1792..2047 -> out[0..255] ===========
    for (int k = b; k < BB; k += G) {
        const int r = D_MODEL + k;
        const float* wrow = WhhF + ((size_t)wave * II + r) * (size_t)II;
        float s = dotH(wrow, hbuf + 4 * (size_t)II, lane);
        s = waveReduce(s);
        if (lane == 0) partial[wave] = s + gihF[wave * BB + k];
        __syncthreads();
        if (tid == 0) {
            const float cc = sigm(partial[1]) * cbuf[r]
                           + sigm(partial[0]) * tanhf(partial[2]);
            out[k] = sigm(partial[3]) * tanhf(cc);
        }
        __syncthreads();
    }
}

extern "C" void kernel_launch(void* const* d_in, const int* in_sizes, int n_in,
                              void* d_out, int out_size, void* d_ws, size_t ws_size,
                              hipStream_t stream) {
    const float* x    = (const float*)d_in[0];
    const float* y    = (const float*)d_in[1];
    const float* Wih5 = (const float*)d_in[2];
    const float* Whh5 = (const float*)d_in[3];
    const float* bih5 = (const float*)d_in[4];
    const float* bhh5 = (const float*)d_in[5];
    const float* WihF = (const float*)d_in[6];
    const float* WhhF = (const float*)d_in[7];
    const float* bihF = (const float*)d_in[8];
    const float* bhhF = (const float*)d_in[9];
    float* out = (float*)d_out;

    int*   ctl    = (int*)d_ws;
    float* fbase  = (float*)((char*)d_ws + 256);
    float* gihAll = fbase;                     // 4*8192
    float* gihF   = gihAll + 4 * FOURI;        // 1024
    float* hbuf   = gihF + 1024;               // 5*2048
    float* cbuf   = hbuf + 5 * II;             // 2048

    // Co-residency by construction: G = min(1024, maxBlocksPerCU * numCU).
    // Host-side queries only — capture-safe (no stream operations).
    int G = 1024;
    int maxB = 0;
    if (hipOccupancyMaxActiveBlocksPerMultiprocessor(&maxB, lstm_pipe, 256, 0)
            == hipSuccess && maxB >= 1) {
        int numCU = 256;
        hipDevice_t dev;
        int cu = 0;
        if (hipGetDevice(&dev) == hipSuccess &&
            hipDeviceGetAttribute(&cu, hipDeviceAttributeMultiprocessorCount,
                                  dev) == hipSuccess && cu > 0)
            numCU = cu;
        long cap = (long)maxB * numCU;
        if (cap < G) G = (int)cap;
        if (G < 1) G = 1;
    }

    // zero the barrier counter (graph-capture-safe async memset)
    hipMemsetAsync(ctl, 0, 64, stream);

    lstm_pipe<<<G, 256, 0, stream>>>(x, y, Wih5, Whh5, bih5, bhh5,
                                     WihF, WhhF, bihF, bhhF, out,
                                     gihAll, gihF, hbuf, cbuf, ctl, G);
}

// Round 5
// 304.277 us; speedup vs baseline: 1.8602x; 1.8602x over previous
//
#include <hip/hip_runtime.h>
#include <cmath>

#define D_MODEL 1792
#define BB      256
#define II      2048          // inner dim
#define FOURI   8192

__device__ __forceinline__ float sigm(float v) { return 1.0f / (1.0f + expf(-v)); }

__device__ __forceinline__ float waveReduce(float s) {
    #pragma unroll
    for (int off = 32; off > 0; off >>= 1) s += __shfl_down(s, off, 64);
    return s;
}

// Agent-coherent scalar accessors: RELAXED atomics bypass stale L1/L2 to the
// coherence point WITHOUT emitting buffer_inv/buffer_wbl2 (which acquire/
// release fences do, and which destroyed R4's streaming bandwidth).
__device__ __forceinline__ float ldc(const float* p) {
    return __hip_atomic_load(p, __ATOMIC_RELAXED, __HIP_MEMORY_SCOPE_AGENT);
}
__device__ __forceinline__ void stc(float* p, float v) {
    __hip_atomic_store(p, v, __ATOMIC_RELAXED, __HIP_MEMORY_SCOPE_AGENT);
}

// dot of one 2048-wide weight row with concat(x_t[1792], y_t[256]) (cached)
__device__ __forceinline__ float dotConcat(const float* __restrict__ wrow,
                                           const float* __restrict__ xt,
                                           const float* __restrict__ yt,
                                           int lane) {
    float sum = 0.f;
    #pragma unroll
    for (int p = 0; p < 8; ++p) {
        const int j = p * 256 + lane * 4;
        float4 w = *(const float4*)(wrow + j);
        float4 v = (p < 7) ? *(const float4*)(xt + j)
                           : *(const float4*)(yt + (j - D_MODEL));
        sum += w.x * v.x + w.y * v.y + w.z * v.z + w.w * v.w;
    }
    return sum;
}

// dot of one 2048-wide weight row (cached) with h staged in LDS
__device__ __forceinline__ float dotLds(const float* __restrict__ wrow,
                                        const float* hs, int lane) {
    float sum = 0.f;
    #pragma unroll
    for (int p = 0; p < 8; ++p) {
        const int j = p * 256 + lane * 4;
        float4 w = *(const float4*)(wrow + j);
        float4 v = *(const float4*)(hs + j);   // ds_read_b128, 2-way = free
        sum += w.x * v.x + w.y * v.y + w.z * v.z + w.w * v.w;
    }
    return sum;
}

__global__ __launch_bounds__(256, 4) void lstm_pipe(
    const float* __restrict__ x,     // (6,1792)
    const float* __restrict__ y,     // (5,256)
    const float* __restrict__ Wih5,  // (5,8192,2048)
    const float* __restrict__ Whh5,  // (5,8192,2048)
    const float* __restrict__ bih5,  // (5,8192)
    const float* __restrict__ bhh5,  // (5,8192)
    const float* __restrict__ WihF,  // (8192,1792)
    const float* __restrict__ WhhF,  // (8192,2048)
    const float* __restrict__ bihF,  // (8192)
    const float* __restrict__ bhhF,  // (8192)
    float* __restrict__ out,         // (256)
    float* __restrict__ gihAll,      // (4,8192) gih for steps 1..4
    float* __restrict__ gihF,        // (1024) compact [gate][256]
    float* __restrict__ hbuf,        // (5,2048)
    float* __restrict__ cbuf,        // (2048)
    int* __restrict__ ctl,           // [0] = barrier counter (pre-zeroed)
    int G)
{
    const int b    = blockIdx.x;
    const int tid  = threadIdx.x;
    const int wave = tid >> 6;
    const int lane = tid & 63;
    __shared__ float hs[II];
    __shared__ float partial[4];

    // Grid barrier, cache-maintenance-free. __syncthreads() drains each
    // wave's vmcnt (incl. agent-scope stores -> globally visible) before
    // s_barrier; the counter is accessed with RELAXED atomics only.
    auto gridbar = [&](int target) {
        __syncthreads();
        if (tid == 0) {
            asm volatile("s_waitcnt vmcnt(0)" ::: "memory");
            __hip_atomic_fetch_add(ctl, 1, __ATOMIC_RELAXED,
                                   __HIP_MEMORY_SCOPE_AGENT);
            while (__hip_atomic_load(ctl, __ATOMIC_RELAXED,
                                     __HIP_MEMORY_SCOPE_AGENT) < target)
                __builtin_amdgcn_s_sleep(8);
        }
        __syncthreads();
    };

    // stage h vector (agent-coherent) into LDS, block-wide
    auto stage_h = [&](const float* hsrc) {
        for (int i = tid; i < II; i += 256) hs[i] = ldc(hsrc + i);
        __syncthreads();
    };

    // ---- one full cell row r for step t (one wave does all gate dots) ----
    auto cell_row = [&](int t, int r) {
        float g[4];
        if (t == 0) {
            #pragma unroll
            for (int q = 0; q < 4; ++q) {
                if (q == 1) { g[1] = 0.f; continue; }   // f-gate unused (c0=0)
                const float* wrow = Wih5 + ((size_t)q * II + r) * (size_t)II;
                float s = dotConcat(wrow, x, y, lane);
                s = waveReduce(s);
                g[q] = s + bih5[q * II + r] + bhh5[q * II + r];
            }
            if (lane == 0) {
                const float cc = sigm(g[0]) * tanhf(g[2]);
                stc(cbuf + r, cc);
                stc(hbuf + r, sigm(g[3]) * tanhf(cc));
            }
        } else {
            const float* W  = Whh5 + (size_t)t * FOURI * II;
            const float* gt = gihAll + (size_t)(t - 1) * FOURI;
            #pragma unroll
            for (int q = 0; q < 4; ++q) {
                const float* wrow = W + ((size_t)q * II + r) * (size_t)II;
                float s = dotLds(wrow, hs, lane);
                s = waveReduce(s);
                g[q] = s + ldc(gt + q * II + r);        // broadcast sc-load
            }
            if (lane == 0) {
                const float cc = sigm(g[1]) * ldc(cbuf + r)
                               + sigm(g[0]) * tanhf(g[2]);
                stc(cbuf + r, cc);
                stc(hbuf + (size_t)t * II + r, sigm(g[3]) * tanhf(cc));
            }
        }
    };

    // ---- one ih row (raw row index 0..8191) for step tt in 1..4 ----
    auto ih_row = [&](int tt, int row) {
        const float* wrow = Wih5 + ((size_t)tt * FOURI + row) * (size_t)II;
        float s = dotConcat(wrow, x + tt * D_MODEL, y + tt * BB, lane);
        s = waveReduce(s);
        if (lane == 0)
            stc(gihAll + (size_t)(tt - 1) * FOURI + row,
                s + bih5[tt * FOURI + row] + bhh5[tt * FOURI + row]);
    };

    // ---- one final-cell ih row, j in [0,1024): gate=j>>8, col=j&255 ----
    auto ihF_row = [&](int j) {
        const int row = (j >> 8) * II + D_MODEL + (j & 255);
        const float* wrow = WihF + (size_t)row * (size_t)D_MODEL;
        const float* x5 = x + 5 * D_MODEL;
        float s = 0.f;
        #pragma unroll
        for (int p = 0; p < 7; ++p) {
            const int jj = p * 256 + lane * 4;
            float4 w = *(const float4*)(wrow + jj);
            float4 v = *(const float4*)(x5 + jj);
            s += w.x * v.x + w.y * v.y + w.z * v.z + w.w * v.w;
        }
        s = waveReduce(s);
        if (lane == 0) stc(gihF + j, s + bihF[row] + bhhF[row]);
    };

    // ======== 5 phases: cell t (waves 0-1) + ih filler (waves 2-3) ========
    for (int t = 0; t < 5; ++t) {
        if (t > 0) stage_h(hbuf + (size_t)(t - 1) * II);
        if (wave < 2) {
            for (int r = 2 * b + wave; r < II; r += 2 * G)
                cell_row(t, r);
        } else if (t < 4) {
            for (int j = b; j < 1024; j += G) {
                const int base = j * 8 + (wave - 2) * 4;
                #pragma unroll
                for (int k = 0; k < 4; ++k) ih_row(t + 1, base + k);
            }
        } else if (wave == 2) {
            for (int j = b; j < 1024; j += G) ihF_row(j);
        }
        gridbar((t + 1) * G);
    }

    // ======== final cell: rows 1792..2047 -> out[0..255] ========
    if (b < BB) {
        stage_h(hbuf + 4 * (size_t)II);
        for (int k = b; k < BB; k += G) {
            const int r = D_MODEL + k;
            const float* wrow = WhhF + ((size_t)wave * II + r) * (size_t)II;
            float s = dotLds(wrow, hs, lane);
            s = waveReduce(s);
            if (lane == 0) partial[wave] = s + ldc(gihF + wave * BB + k);
            __syncthreads();
            if (tid == 0) {
                const float cc = sigm(partial[1]) * ldc(cbuf + r)
                               + sigm(partial[0]) * tanhf(partial[2]);
                out[k] = sigm(partial[3]) * tanhf(cc);
            }
            __syncthreads();
        }
    }
}

extern "C" void kernel_launch(void* const* d_in, const int* in_sizes, int n_in,
                              void* d_out, int out_size, void* d_ws, size_t ws_size,
                              hipStream_t stream) {
    const float* x    = (const float*)d_in[0];
    const float* y    = (const float*)d_in[1];
    const float* Wih5 = (const float*)d_in[2];
    const float* Whh5 = (const float*)d_in[3];
    const float* bih5 = (const float*)d_in[4];
    const float* bhh5 = (const float*)d_in[5];
    const float* WihF = (const float*)d_in[6];
    const float* WhhF = (const float*)d_in[7];
    const float* bihF = (const float*)d_in[8];
    const float* bhhF = (const float*)d_in[9];
    float* out = (float*)d_out;

    int*   ctl    = (int*)d_ws;
    float* fbase  = (float*)((char*)d_ws + 256);
    float* gihAll = fbase;                     // 4*8192
    float* gihF   = gihAll + 4 * FOURI;        // 1024
    float* hbuf   = gihF + 1024;               // 5*2048
    float* cbuf   = hbuf + 5 * II;             // 2048

    // Co-residency by construction (capture-safe host-side queries only).
    int G = 1024;
    int maxB = 0;
    if (hipOccupancyMaxActiveBlocksPerMultiprocessor(&maxB, lstm_pipe, 256, 0)
            == hipSuccess && maxB >= 1) {
        int numCU = 256;
        hipDevice_t dev;
        int cu = 0;
        if (hipGetDevice(&dev) == hipSuccess &&
            hipDeviceGetAttribute(&cu, hipDeviceAttributeMultiprocessorCount,
                                  dev) == hipSuccess && cu > 0)
            numCU = cu;
        long cap = (long)maxB * numCU;
        if (cap < G) G = (int)cap;
        if (G < 1) G = 1;
    }

    hipMemsetAsync(ctl, 0, 64, stream);   // zero barrier counter (in-graph)

    lstm_pipe<<<G, 256, 0, stream>>>(x, y, Wih5, Whh5, bih5, bhh5,
                                     WihF, WhhF, bihF, bhhF, out,
                                     gihAll, gihF, hbuf, cbuf, ctl, G);
}